// Round 9
// baseline (214.087 us; speedup 1.0000x reference)
//
#include <hip/hip_runtime.h>
#include <math.h>

// Problem constants
#define BB 2
#define TT 1024
#define CC 1024
#define HH 16
#define HD 64
#define SS 512
#define LL 1024
#define ST 1536   // S+T
#define MM 2560   // L+S+T
#define C3 3072   // 3*C

typedef __attribute__((ext_vector_type(8))) short short8;    // 8 bf16 (4 VGPRs)
typedef __attribute__((ext_vector_type(4))) short short4v;
typedef __attribute__((ext_vector_type(4))) float floatx4;

__device__ __forceinline__ unsigned short f2bf(float f) {
    union { float f; unsigned u; } v; v.f = f;
    unsigned r = v.u + 0x7fffu + ((v.u >> 16) & 1u);   // RNE
    return (unsigned short)(r >> 16);
}
// cheap round-half-up bf16 (2 VALU); fine for p >= 0 softmax weights
__device__ __forceinline__ unsigned short p2bf(float f) {
    union { float f; unsigned u; } v; v.f = f;
    return (unsigned short)((v.u + 0x8000u) >> 16);
}
__device__ __forceinline__ float bf2f(short s) {
    union { unsigned u; float f; } v;
    v.u = ((unsigned)(unsigned short)s) << 16;
    return v.f;
}

// exp2 on the transcendental unit; argument pre-scaled by 0.125*log2(e)
#if __has_builtin(__builtin_amdgcn_exp2f)
#define EXPP(x) __builtin_amdgcn_exp2f(x)
#else
#define EXPP(x) __expf((x) * 0.69314718056f)
#endif
#define SCL 0.18033688011112042f   // 0.125 * log2(e)

// async global->LDS, 16B per lane; LDS side is wave-uniform base + lane*16
__device__ __forceinline__ void gl_lds16(const short* g, short* l) {
    __builtin_amdgcn_global_load_lds(
        (const __attribute__((address_space(1))) void*)g,
        (__attribute__((address_space(3))) void*)l,
        16, 0, 0);
}

// ---------------------------------------------------------------------------
// prep_all: all independent prep work in ONE launch, partitioned by blockIdx.
// ---------------------------------------------------------------------------
__global__ __launch_bounds__(256)
void prep_all(const float* __restrict__ x, const float* __restrict__ stm,
              const float* __restrict__ w_attn, const float* __restrict__ w_proj,
              const float* __restrict__ lk, const float* __restrict__ lv,
              short* __restrict__ Xb, short* __restrict__ WaT,
              short* __restrict__ WpT, short* __restrict__ Kg,
              short* __restrict__ Vt, float* __restrict__ tab)
{
    __shared__ __align__(16) char smem[9216];
    const int blk = blockIdx.x;
    const int t = threadIdx.x;

    if (blk < 3072) {
        // ---- cast_xcat ----
        const int idx = blk * 256 + t;
        const int rg  = idx >> 8;
        const int c   = (idx & 255) << 2;
        const int b   = rg >= ST;
        const int r   = rg - b * ST;
        const float* src = (r < SS) ? (stm + ((size_t)b * SS + r) * CC + c)
                                    : (x   + ((size_t)b * TT + (r - SS)) * CC + c);
        float4 v = *(const float4*)src;
        short4v o;
        o.x = (short)f2bf(v.x); o.y = (short)f2bf(v.y);
        o.z = (short)f2bf(v.z); o.w = (short)f2bf(v.w);
        *(short4v*)(Xb + (size_t)rg * CC + c) = o;
    } else if (blk < 7168) {
        // ---- weight transpose+cast ----
        const bool isA = blk < 6144;
        const int bx = isA ? (blk - 3072) : (blk - 6144);
        const int nblk = isA ? 96 : 32;
        const int Nd = isA ? C3 : CC;
        const float* W = isA ? w_attn : w_proj;
        short* WT = isA ? WaT : WpT;
        const int n0 = (bx % nblk) * 32, k0 = (bx / nblk) * 32;
        float (*Tl)[33] = (float(*)[33])smem;
        const int r = t >> 3, c4 = (t & 7) << 2;
        float4 v = *(const float4*)(W + (size_t)(k0 + r) * Nd + n0 + c4);
        Tl[r][c4 + 0] = v.x; Tl[r][c4 + 1] = v.y;
        Tl[r][c4 + 2] = v.z; Tl[r][c4 + 3] = v.w;
        __syncthreads();
        short4v o;
        o.x = (short)f2bf(Tl[c4 + 0][r]); o.y = (short)f2bf(Tl[c4 + 1][r]);
        o.z = (short)f2bf(Tl[c4 + 2][r]); o.w = (short)f2bf(Tl[c4 + 3][r]);
        *(short4v*)(WT + (size_t)(n0 + r) * CC + k0 + c4) = o;
    } else if (blk < 7360) {
        // ---- rope table ----
        const int idx = (blk - 7168) * 256 + t;   // < 49152
        const int r = idx >> 5, e = idx & 31;
        const float inv = powf(10000.0f, -(float)e * (1.0f / 32.0f));
        float sn, cs;
        sincosf((float)r * inv, &sn, &cs);
        tab[idx * 2] = cs;
        tab[idx * 2 + 1] = sn;
    } else {
        // ---- long_k -> Kb (cast), long_v -> Vtr (cast + transpose) ----
        const int bx = blk - 7360;                 // < 512
        const int bh = bx >> 4, j0 = (bx & 15) * 64;
        const int b = bh >> 4, h = bh & 15;
        short (*Tl)[72] = (short(*)[72])smem;
        const int jr = t >> 2, c16 = (t & 3) << 4;
        const size_t si = (((size_t)b * LL + j0 + jr) * HH + h) * HD + c16;
        short kk[16], vv[16];
        #pragma unroll
        for (int u = 0; u < 4; u++) {
            float4 kv = *(const float4*)(lk + si + 4 * u);
            float4 vf = *(const float4*)(lv + si + 4 * u);
            kk[4*u+0] = (short)f2bf(kv.x); kk[4*u+1] = (short)f2bf(kv.y);
            kk[4*u+2] = (short)f2bf(kv.z); kk[4*u+3] = (short)f2bf(kv.w);
            vv[4*u+0] = (short)f2bf(vf.x); vv[4*u+1] = (short)f2bf(vf.y);
            vv[4*u+2] = (short)f2bf(vf.z); vv[4*u+3] = (short)f2bf(vf.w);
        }
        short* kdst = Kg + ((size_t)bh * MM + j0 + jr) * HD + c16;
        *(short8*)kdst       = *(short8*)&kk[0];
        *(short8*)(kdst + 8) = *(short8*)&kk[8];
        #pragma unroll
        for (int u = 0; u < 16; u++) Tl[jr][c16 + u] = vv[u];
        __syncthreads();
        const int r = t >> 2, c = t & 3;    // r = d index, c = j chunk
        short o0[8], o1[8];
        #pragma unroll
        for (int u = 0; u < 8; u++) {
            o0[u] = Tl[c * 16 + u][r];
            o1[u] = Tl[c * 16 + 8 + u][r];
        }
        short* vdst = Vt + ((size_t)bh * HD + r) * MM + j0 + c * 16;
        *(short8*)vdst       = *(short8*)&o0[0];
        *(short8*)(vdst + 8) = *(short8*)&o1[0];
    }
}

// ---------------------------------------------------------------------------
// Kernel: qkv MFMA GEMM (unchanged — async staging, RoPE table,
// LDS-staged coalesced stores, V written directly transposed)
// ---------------------------------------------------------------------------
__global__ __launch_bounds__(256)
void qkv_gemm(const short* __restrict__ A, const short* __restrict__ Bt,
              const float* __restrict__ RT,
              short* __restrict__ Qo, short* __restrict__ Ko, short* __restrict__ Vo)
{
    __shared__ short As[128 * 32];
    __shared__ short Bs[128 * 32];
    __shared__ short Et[128 * 132];
    const int b = blockIdx.z;
    const int row0 = blockIdx.y * 128, col0 = blockIdx.x * 128;
    const int tid = threadIdx.x;
    const int w = tid >> 6, l = tid & 63, quad = l >> 4, cl = l & 15;
    const int wr = w >> 1, wc = w & 1;

    const int reg  = col0 >> 10;
    const bool hasQ = (row0 >= SS);
    if (reg == 0 && !hasQ) return;

    const int srow = (l >> 2);
    const int schunk = ((l & 3) - (srow >> 1)) & 3;
    const int arow = w * 32 + srow;
    const short* gA0 = A + ((size_t)b * ST + row0 + arow) * CC + schunk * 8;
    const short* gA1 = gA0 + (size_t)16 * CC;
    const short* gB0 = Bt + (size_t)(col0 + arow) * CC + schunk * 8;
    const short* gB1 = gB0 + (size_t)16 * CC;
    short* lA0 = &As[(w * 32) * 32 + l * 8];
    short* lA1 = &As[(w * 32 + 16) * 32 + l * 8];
    short* lB0 = &Bs[(w * 32) * 32 + l * 8];
    short* lB1 = &Bs[(w * 32 + 16) * 32 + l * 8];

    const int fs = (quad + (cl >> 1)) & 3;

    floatx4 acc[4][4];
    #pragma unroll
    for (int mi = 0; mi < 4; mi++)
        #pragma unroll
        for (int ni = 0; ni < 4; ni++) acc[mi][ni] = (floatx4){0.f, 0.f, 0.f, 0.f};

    for (int k0 = 0; k0 < CC; k0 += 32) {
        __syncthreads();
        gl_lds16(gA0 + k0, lA0);
        gl_lds16(gA1 + k0, lA1);
        gl_lds16(gB0 + k0, lB0);
        gl_lds16(gB1 + k0, lB1);
        __syncthreads();
        short8 af[4], bf[4];
        #pragma unroll
        for (int mi = 0; mi < 4; mi++)
            af[mi] = *(const short8*)&As[(wr * 64 + mi * 16 + cl) * 32 + fs * 8];
        #pragma unroll
        for (int ni = 0; ni < 4; ni++)
            bf[ni] = *(const short8*)&Bs[(wc * 64 + ni * 16 + cl) * 32 + fs * 8];
        #pragma unroll
        for (int mi = 0; mi < 4; mi++)
            #pragma unroll
            for (int ni = 0; ni < 4; ni++)
                acc[mi][ni] = __builtin_amdgcn_mfma_f32_16x16x32_bf16(
                    af[mi], bf[ni], acc[mi][ni], 0, 0, 0);
    }

    #pragma unroll
    for (int ni = 0; ni < 4; ni++) {
        const int c_local = wc * 64 + ni * 16 + cl;
        const int e = (c_local & 63) >> 1;
        #pragma unroll
        for (int mi = 0; mi < 4; mi++) {
            #pragma unroll
            for (int r = 0; r < 4; r++) {
                const int R_local = wr * 64 + mi * 16 + quad * 4 + r;
                const int R = row0 + R_local;
                float v = acc[mi][ni][r];
                if (reg < 2) {
                    const float2 tt = ((const float2*)RT)[R * 32 + e];
                    float po = __shfl_xor(v, 1);
                    float out = ((cl & 1) == 0) ? (v * tt.x - po * tt.y)
                                                : (po * tt.y + v * tt.x);
                    unsigned short bfv = f2bf(out);
                    int ob = __shfl_xor((int)bfv, 1);
                    if ((cl & 1) == 0) {
                        unsigned word = (unsigned)bfv | (((unsigned)ob & 0xffffu) << 16);
                        *(unsigned*)&Et[R_local * 132 + c_local] = word;
                    }
                } else {
                    Et[c_local * 132 + R_local] = (short)f2bf(v);
                }
            }
        }
    }
    __syncthreads();

    const int hh0 = (col0 & 1023) >> 6;
    if (reg < 2) {
        #pragma unroll
        for (int hf = 0; hf < 2; hf++) {
            const int hh = hh0 + hf;
            short* dstb = (reg == 0)
                ? Qo + (((size_t)b * HH + hh) * TT + (row0 - SS)) * HD
                : Ko + (((size_t)b * HH + hh) * MM + LL + row0) * HD;
            #pragma unroll
            for (int it = 0; it < 4; it++) {
                const int idx = it * 2048 + tid * 8;
                const int r = idx >> 6, d = idx & 63;
                short4v v0 = *(const short4v*)&Et[r * 132 + hf * 64 + d];
                short4v v1 = *(const short4v*)&Et[r * 132 + hf * 64 + d + 4];
                short8 vv;
                #pragma unroll
                for (int u = 0; u < 4; u++) { vv[u] = v0[u]; vv[u + 4] = v1[u]; }
                *(short8*)(dstb + idx) = vv;
            }
        }
    } else {
        #pragma unroll
        for (int it = 0; it < 8; it++) {
            const int idx = it * 2048 + tid * 8;
            const int c = idx >> 7, r0 = idx & 127;
            const int hh = hh0 + (c >> 6), d = c & 63;
            short4v v0 = *(const short4v*)&Et[c * 132 + r0];
            short4v v1 = *(const short4v*)&Et[c * 132 + r0 + 4];
            short8 vv;
            #pragma unroll
            for (int u = 0; u < 4; u++) { vv[u] = v0[u]; vv[u + 4] = v1[u]; }
            *(short8*)(Vo + (((size_t)b * HH + hh) * HD + d) * MM + LL + row0 + r0) = vv;
        }
    }
}

// ---------------------------------------------------------------------------
// Kernel: MFMA flash attention v3.2 (round-8 verified structure +
//   exp2-folded scale and 2-op P rounding in the inner loop).
// ---------------------------------------------------------------------------
#define PSP 72
#define PSW (32 * PSP)
#define VS_OFF 4096
#define PS_OFF 8192
__global__ __launch_bounds__(256, 4)
void attn_mfma(const short* __restrict__ Qg, const short* __restrict__ Kg,
               const short* __restrict__ Vt, short* __restrict__ Op,
               float* __restrict__ Lp)
{
    // L layout (shorts): [0,4096) Ks | [4096,8192) Vs | [8192,17408) Ps
    __shared__ __align__(16) short L[17408];

    const int bh = blockIdx.x;
    const int q0 = (7 - blockIdx.y) * 128;   // heavy blocks dispatch first
    const int piece = blockIdx.z;            // 0..3 split-K
    const int tid = threadIdx.x, w = tid >> 6, l = tid & 63;
    const int quad = l >> 4, cl = l & 15;

    short8 qa[2][2];
    #pragma unroll
    for (int g = 0; g < 2; g++) {
        const short* qptr = Qg + ((size_t)bh * TT + q0 + w * 32 + g * 16 + cl) * HD + quad * 8;
        qa[g][0] = *(const short8*)qptr;
        qa[g][1] = *(const short8*)(qptr + 32);
    }

    floatx4 o[2][4];
    float rs[2][4];
    #pragma unroll
    for (int g = 0; g < 2; g++)
        #pragma unroll
        for (int r = 0; r < 4; r++) {
            rs[g][r] = 0.f;
            o[g][r] = (floatx4){0.f, 0.f, 0.f, 0.f};
        }

    const int srow_lo = l >> 3;
    const int sslot  = l & 7;
    const int ch0 = (sslot - (srow_lo >> 1)) & 7;
    const int ch1 = (sslot - (4 + (srow_lo >> 1))) & 7;
    const int rowi0 = w * 16 + srow_lo;
    const int rowi1 = w * 16 + 8 + srow_lo;
    const short* kgb = Kg + (size_t)bh * MM * HD;
    const short* vbase = Vt + (size_t)bh * HD * MM;
    short* ldsK0 = &L[(w * 16) * 64];
    short* ldsK1 = &L[(w * 16 + 8) * 64];
    short* ldsV0 = &L[VS_OFF + (w * 16) * 64];
    short* ldsV1 = &L[VS_OFF + (w * 16 + 8) * 64];

    const int fsA = (quad + (cl >> 1)) & 7;
    const int fsB = (quad + 4 + (cl >> 1)) & 7;
    const int psA = (quad + 2 * cl) & 7;
    const int psB = (quad + 4 + 2 * cl) & 7;

    const int ntiles = (LL + SS + q0) / 64 + 2;
    const int t_begin = piece * ntiles / 4;
    const int t_end   = (piece + 1) * ntiles / 4;

    for (int t = t_begin; t < t_end; t++) {
        const int j0 = t * 64;
        __syncthreads();
        gl_lds16(kgb + (size_t)(j0 + rowi0) * HD + ch0 * 8, ldsK0);
        gl_lds16(kgb + (size_t)(j0 + rowi1) * HD + ch1 * 8, ldsK1);
        gl_lds16(vbase + (size_t)rowi0 * MM + j0 + ch0 * 8, ldsV0);
        gl_lds16(vbase + (size_t)rowi1 * MM + j0 + ch1 * 8, ldsV1);
        __syncthreads();

        // ---- S = Q.K^T for both q-groups (shared K frag reads) ----
        floatx4 s[2][4];
        #pragma unroll
        for (int ks = 0; ks < 4; ks++) {
            const int krow = ks * 16 + cl;
            short8 kf0 = *(const short8*)&L[krow * 64 + fsA * 8];
            short8 kf1 = *(const short8*)&L[krow * 64 + fsB * 8];
            #pragma unroll
            for (int g = 0; g < 2; g++) {
                floatx4 z = (floatx4){0.f, 0.f, 0.f, 0.f};
                z = __builtin_amdgcn_mfma_f32_16x16x32_bf16(qa[g][0], kf0, z, 0, 0, 0);
                z = __builtin_amdgcn_mfma_f32_16x16x32_bf16(qa[g][1], kf1, z, 0, 0, 0);
                s[g][ks] = z;
            }
        }

        // ---- no-max softmax: p = exp2(s * 0.125*log2e); per-lane sums ----
        const bool tailzone = (t >= ntiles - 2);
        #pragma unroll
        for (int g = 0; g < 2; g++) {
            const int qgb = LL + SS + q0 + w * 32 + g * 16;
            #pragma unroll
            for (int ks = 0; ks < 4; ks++) {
                #pragma unroll
                for (int r = 0; r < 4; r++) {
                    float sv = s[g][ks][r] * SCL;
                    if (tailzone && (j0 + ks * 16 + cl > qgb + quad * 4 + r))
                        sv = -INFINITY;
                    const float p = EXPP(sv);
                    rs[g][r] += p;
                    const int qrw = quad * 4 + r;
                    const int slot = (ks * 2 + (cl >> 3) + 2 * qrw) & 7;
                    L[PS_OFF + w * PSW + (g * 16 + qrw) * PSP + slot * 8 + (cl & 7)] =
                        (short)p2bf(p);
                }
            }
        }

        __builtin_amdgcn_s_waitcnt(0xc07f);   // lgkmcnt(0)
        __builtin_amdgcn_wave_barrier();

        // ---- O += P.V (shared V frag reads) ----
        short8 pf[2][2];
        #pragma unroll
        for (int g = 0; g < 2; g++) {
            pf[g][0] = *(const short8*)&L[PS_OFF + w * PSW + (g * 16 + cl) * PSP + psA * 8];
            pf[g][1] = *(const short8*)&L[PS_OFF + w * PSW + (g * 16 + cl) * PSP + psB * 8];
        }
        #pragma unroll
        for (int nt = 0; nt < 4; nt++) {
            const int drow = nt * 16 + cl;
            short8 vf0 = *(const short8*)&L[VS_OFF + drow * 64 + fsA * 8];
            short8 vf1 = *(const short8*)&L[VS_OFF + drow * 64 + fsB * 8];
            #pragma unroll
            for (int g = 0; g < 2; g++) {
                o[g][nt] = __builtin_amdgcn_mfma_f32_16x16x32_bf16(pf[g][0], vf0, o[g][nt], 0, 0, 0);
                o[g][nt] = __builtin_amdgcn_mfma_f32_16x16x32_bf16(pf[g][1], vf1, o[g][nt], 0, 0, 0);
            }
        }
    }

    // ---- deferred l reduction ----
    #pragma unroll
    for (int g = 0; g < 2; g++)
        #pragma unroll
        for (int r = 0; r < 4; r++) {
            float t2 = rs[g][r];
            t2 += __shfl_xor(t2, 1);
            t2 += __shfl_xor(t2, 2);
            t2 += __shfl_xor(t2, 4);
            t2 += __shfl_xor(t2, 8);
            if (cl == 0)
                Lp[piece * 32768 + bh * 1024 + q0 + w * 32 + g * 16 + quad * 4 + r] = t2;
        }

    // ---- stage raw partial O -> coalesced store ----
    __syncthreads();
    #pragma unroll
    for (int g = 0; g < 2; g++)
        #pragma unroll
        for (int r = 0; r < 4; r++) {
            const int ql = w * 32 + g * 16 + quad * 4 + r;
            #pragma unroll
            for (int nt = 0; nt < 4; nt++)
                L[ql * 68 + nt * 16 + cl] = (short)f2bf(o[g][nt][r]);
        }
    __syncthreads();
    short* ob = Op + ((size_t)(piece * 32 + bh) * 1024 + q0) * 64;
    #pragma unroll
    for (int it = 0; it < 4; it++) {
        const int idx = it * 2048 + tid * 8;
        const int q = idx >> 6, d = idx & 63;
        short4v v0 = *(const short4v*)&L[q * 68 + d];
        short4v v1 = *(const short4v*)&L[q * 68 + d + 4];
        short8 vv;
        #pragma unroll
        for (int u = 0; u < 4; u++) { vv[u] = v0[u]; vv[u + 4] = v1[u]; }
        *(short8*)(ob + idx) = vv;
    }
}

// ---------------------------------------------------------------------------
// Kernel: proj MFMA GEMM with FUSED split-K combine. A-tile is built in the
// staging path: sum 4 bf16 partials, scale by 1/l (per row,head), cvt to
// bf16, swizzled ds_write. B stays on global_load_lds. h = k/64 is uniform
// per k-iteration, so 1/l costs 5 scalar ops per 2 iterations.
// ---------------------------------------------------------------------------
__global__ __launch_bounds__(256)
void proj_gemm(const short* __restrict__ Op, const float* __restrict__ Lp,
               const short* __restrict__ Bt, float* __restrict__ Co)
{
    __shared__ short As[64 * 32];
    __shared__ short Bs[64 * 32];
    const int row0 = blockIdx.y * 64, col0 = blockIdx.x * 64;
    const int tid = threadIdx.x;
    const int w = tid >> 6, l = tid & 63, quad = l >> 4, cl = l & 15;
    const int wr = w >> 1, wc = w & 1;

    // B async staging (unchanged scheme)
    const int srow = tid >> 2;
    const int schunk = ((tid & 3) - ((srow & 15) >> 1)) & 3;
    const short* gB = Bt + (size_t)(col0 + srow) * CC + schunk * 8;
    short* lB = &Bs[tid * 8];

    // A manual staging: thread covers row ar, chunk ac (8 k)
    const int ar = tid >> 2, ac = tid & 3;
    const int aslot = (ac + ((ar & 15) >> 1)) & 3;
    short* aw = &As[ar * 32 + aslot * 8];
    const int b = row0 >> 10;
    const int q = (row0 & 1023) + ar;

    const int fs = (quad + (cl >> 1)) & 3;

    floatx4 acc[2][2];
    #pragma unroll
    for (int mi = 0; mi < 2; mi++)
        #pragma unroll
        for (int ni = 0; ni < 2; ni++) acc[mi][ni] = (floatx4){0.f, 0.f, 0.f, 0.f};

    for (int h = 0; h < HH; h++) {
        const int lrow = (b * HH + h) * 1024 + q;
        const float lsum = Lp[lrow] + Lp[32768 + lrow] + Lp[65536 + lrow] + Lp[98304 + lrow];
        const float linv = 1.0f / lsum;
        const short* opb = Op + ((size_t)(b * HH + h) * 1024 + q) * 64;
        #pragma unroll
        for (int kk = 0; kk < 2; kk++) {
            const int k0 = h * 64 + kk * 32;
            const int d0 = kk * 32 + ac * 8;
            __syncthreads();
            gl_lds16(gB + k0, lB);
            float a8[8] = {0.f, 0.f, 0.f, 0.f, 0.f, 0.f, 0.f, 0.f};
            #pragma unroll
            for (int p = 0; p < 4; p++) {
                short8 v = *(const short8*)(opb + (size_t)p * 2097152 + d0);
                #pragma unroll
                for (int u = 0; u < 8; u++) a8[u] += bf2f(v[u]);
            }
            short8 w8;
            #pragma unroll
            for (int u = 0; u < 8; u++) w8[u] = (short)f2bf(a8[u] * linv);
            *(short8*)aw = w8;
            __syncthreads();
            short8 af[2], bf[2];
            #pragma unroll
            for (int mi = 0; mi < 2; mi++)
                af[mi] = *(const short8*)&As[(wr * 32 + mi * 16 + cl) * 32 + fs * 8];
            #pragma unroll
            for (int ni = 0; ni < 2; ni++)
                bf[ni] = *(const short8*)&Bs[(wc * 32 + ni * 16 + cl) * 32 + fs * 8];
            #pragma unroll
            for (int mi = 0; mi < 2; mi++)
                #pragma unroll
                for (int ni = 0; ni < 2; ni++)
                    acc[mi][ni] = __builtin_amdgcn_mfma_f32_16x16x32_bf16(
                        af[mi], bf[ni], acc[mi][ni], 0, 0, 0);
        }
    }
    #pragma unroll
    for (int mi = 0; mi < 2; mi++)
        #pragma unroll
        for (int ni = 0; ni < 2; ni++)
            #pragma unroll
            for (int r = 0; r < 4; r++)
                Co[(size_t)(row0 + wr * 32 + mi * 16 + quad * 4 + r) * CC
                   + col0 + wc * 32 + ni * 16 + cl] = acc[mi][ni][r];
}

// ---------------------------------------------------------------------------
extern "C" void kernel_launch(void* const* d_in, const int* in_sizes, int n_in,
                              void* d_out, int out_size, void* d_ws, size_t ws_size,
                              hipStream_t stream)
{
    (void)in_sizes; (void)n_in; (void)out_size; (void)ws_size;
    const float* x      = (const float*)d_in[0];
    const float* stm    = (const float*)d_in[1];
    // d_in[2] = long_q: unused (output slice only covers query rows >= L+S)
    const float* long_k = (const float*)d_in[3];
    const float* long_v = (const float*)d_in[4];
    const float* w_attn = (const float*)d_in[5];
    const float* w_proj = (const float*)d_in[6];
    float* out = (float*)d_out;

    short* Xb   = (short*)d_ws;                 // 3,145,728
    short* WaT  = Xb   + (size_t)3145728;       // 3,145,728
    short* WpT  = WaT  + (size_t)3145728;       // 1,048,576
    short* Qb   = WpT  + (size_t)1048576;       // 2,097,152
    short* Kb   = Qb   + (size_t)2097152;       // 5,242,880
    short* Vtr  = Kb   + (size_t)5242880;       // 5,242,880
    short* Yb   = Vtr  + (size_t)5242880;       // 2,097,152 (unused, kept for layout)
    float* RTab = (float*)(Yb + (size_t)2097152);     // 98,304 floats
    short* Opart = (short*)(RTab + 98304);            // 8,388,608 shorts (4 pieces)
    float* Lpart = (float*)(Opart + (size_t)8388608); // 131,072 floats

    prep_all<<<7872, 256, 0, stream>>>(x, stm, w_attn, w_proj, long_k, long_v,
                                       Xb, WaT, WpT, Kb, Vtr, RTab);

    qkv_gemm<<<dim3(24, 12, 2), 256, 0, stream>>>(Xb, WaT, RTab, Qb, Kb, Vtr);

    attn_mfma<<<dim3(32, 8, 4), 256, 0, stream>>>(Qb, Kb, Vtr, Opart, Lpart);

    proj_gemm<<<dim3(16, 32), 256, 0, stream>>>(Opart, Lpart, WpT, out);
}